// Round 4
// baseline (4067.834 us; speedup 1.0000x reference)
//
#include <hip/hip_runtime.h>
#include <stdint.h>
#include <math.h>

#define VV 128000
#define DD 2048
#define BB 32
#define SS 8
#define NCAND 4096

// jax_threefry_partitionable (default True since jax 0.4.36) 32-bit bit stream:
//   counts1, counts2 = iota_2x32_shape(shape)    # (hi, lo) of 64-bit flat iota
//   bits1, bits2 = threefry2x32(key, counts1, counts2)
//   bits = bits1 ^ bits2                          # 32-bit output path
// For flat < 2^32: counter = (0, flat); bits = o0 ^ o1.
#define TF_VARIANT 1

// ---------------- threefry2x32 core (key = (0, 42) from jax.random.key(42)) ----------------
__device__ __forceinline__ uint32_t rotl32(uint32_t x, uint32_t r) {
    return (x << r) | (x >> (32u - r));
}

__device__ __forceinline__ void threefry2x32(uint32_t c0, uint32_t c1,
                                             uint32_t& o0, uint32_t& o1) {
    const uint32_t k0 = 0u, k1 = 42u;
    const uint32_t k2 = 0x1BD11BDAu ^ k0 ^ k1;
    uint32_t x0 = c0 + k0;
    uint32_t x1 = c1 + k1;
    #define TF_ROUND(r) { x0 += x1; x1 = rotl32(x1, r); x1 ^= x0; }
    TF_ROUND(13) TF_ROUND(15) TF_ROUND(26) TF_ROUND(6)
    x0 += k1; x1 += k2 + 1u;
    TF_ROUND(17) TF_ROUND(29) TF_ROUND(16) TF_ROUND(24)
    x0 += k2; x1 += k0 + 2u;
    TF_ROUND(13) TF_ROUND(15) TF_ROUND(26) TF_ROUND(6)
    x0 += k0; x1 += k1 + 3u;
    TF_ROUND(17) TF_ROUND(29) TF_ROUND(16) TF_ROUND(24)
    x0 += k1; x1 += k2 + 4u;
    TF_ROUND(13) TF_ROUND(15) TF_ROUND(26) TF_ROUND(6)
    x0 += k2; x1 += k0 + 5u;
    #undef TF_ROUND
    o0 = x0; o1 = x1;
}

__device__ float gumbel_at(uint32_t flat) {
    uint32_t o0, o1;
#if TF_VARIANT == 2
    threefry2x32(flat, 0u, o0, o1);
    uint32_t bits = o0;
#else
    threefry2x32(0u, flat, o0, o1);   // counter (hi=0, lo=flat)
#if TF_VARIANT == 0
    uint32_t bits = o0;
#else
    uint32_t bits = o0 ^ o1;          // partitionable 32-bit path
#endif
#endif
    // exact jax.random.uniform(minval=tiny) -> gumbel
    uint32_t fb = (bits >> 9) | 0x3F800000u;
    float f = __uint_as_float(fb) - 1.0f;       // [0,1), multiples of 2^-23
    const float TINY = 1.17549435e-38f;
    float u = (f > 0.0f) ? f : TINY;            // == max(tiny, f*(1-tiny)+tiny) in fp32
    return -logf(-logf(u));
}

__device__ __forceinline__ uint32_t enc_f32(float f) {
    uint32_t u = __float_as_uint(f);
    return u ^ (0x80000000u | (uint32_t)(((int32_t)u) >> 31));  // order-preserving
}

// ---------------- K1: logits = softcap(hs @ emb^T)/temp ----------------
// grid 8000 x 256 threads; block owns 16 v rows; 16 lanes split D per row.
__global__ __launch_bounds__(256, 4) void gemv_kernel(
    const float* __restrict__ emb, const float* __restrict__ hidden,
    const int* __restrict__ outpos, const float* __restrict__ temps,
    float* __restrict__ out)
{
    __shared__ float hs[BB][256];      // 32KB D-chunk of hidden states
    __shared__ float lout[16][33];     // transpose buffer (padded stride 33)

    const int tid = threadIdx.x;
    const int vi  = tid >> 4;          // 0..15: v row within block
    const int dl  = tid & 15;          // 0..15: D-slice lane
    const int vbase = blockIdx.x * 16;
    const int v = vbase + vi;
    const int pos = outpos[0];

    float acc[BB];
    #pragma unroll
    for (int b = 0; b < BB; ++b) acc[b] = 0.0f;

    const float* erow = emb + (size_t)v * DD;

    for (int cc = 0; cc < DD / 256; ++cc) {
        __syncthreads();
        #pragma unroll
        for (int k = 0; k < 8; ++k) {
            int q   = tid + k * 256;   // float4 index, 2048 per chunk
            int row = q >> 6;          // 64 float4 per row
            int c4  = q & 63;
            const float4 hv = *reinterpret_cast<const float4*>(
                hidden + (size_t)row * (SS * DD) + (size_t)pos * DD + cc * 256 + c4 * 4);
            *reinterpret_cast<float4*>(&hs[row][c4 * 4]) = hv;
        }
        __syncthreads();
        #pragma unroll
        for (int j = 0; j < 4; ++j) {
            const int dloc = j * 64 + dl * 4;
            const float4 e = *reinterpret_cast<const float4*>(erow + cc * 256 + dloc);
            #pragma unroll
            for (int b = 0; b < BB; ++b) {
                const float4 h = *reinterpret_cast<const float4*>(&hs[b][dloc]);
                acc[b] += e.x * h.x;
                acc[b] += e.y * h.y;
                acc[b] += e.z * h.z;
                acc[b] += e.w * h.w;
            }
        }
    }

    #pragma unroll
    for (int b = 0; b < BB; ++b) {
        float a = acc[b];
        a += __shfl_xor(a, 1, 64);
        a += __shfl_xor(a, 2, 64);
        a += __shfl_xor(a, 4, 64);
        a += __shfl_xor(a, 8, 64);
        acc[b] = a;
    }
    __syncthreads();
    if (dl == 0) {
        #pragma unroll
        for (int b = 0; b < BB; ++b) {
            float raw = acc[b];
            float l = tanhf(raw / 30.0f) * 30.0f;   // final logit softcapping
            l = l / temps[b];                        // temperature
            lout[vi][b] = l;
        }
    }
    __syncthreads();
    #pragma unroll
    for (int r = 0; r < 2; ++r) {
        int idx = tid + r * 256;
        int b2  = idx >> 4;
        int vv2 = idx & 15;
        out[32 + (size_t)b2 * VV + vbase + vv2] = lout[vv2][b2];
    }
}

// ---------------- K2: per-row top-64 (prob-sorted, stable) + exact-RNG categorical ----------------
__global__ __launch_bounds__(1024) void sample_kernel(
    float* __restrict__ dout, const float* __restrict__ top_ps,
    const int* __restrict__ top_ks)
{
    const int b   = blockIdx.x;
    const int tid = threadIdx.x;
    const float* row = dout + 32 + (size_t)b * VV;

    __shared__ unsigned int hist[2048];            // 8KB
    __shared__ unsigned long long arr[NCAND];      // 32KB: (enc(p)<<32)|~idx
    __shared__ float red[1024];                    // 4KB
    __shared__ float m_sh;
    __shared__ unsigned int thresh_sh;
    __shared__ unsigned int cnt_sh;
    __shared__ float p_arr[64];
    __shared__ unsigned int idx_arr[64];
    __shared__ float S_sh;
    __shared__ unsigned long long keep_sh;

    for (int i = tid; i < 2048; i += 1024) hist[i] = 0u;
    for (int i = tid; i < NCAND; i += 1024) arr[i] = 0ull;
    if (tid == 0) cnt_sh = 0u;
    __syncthreads();

    // ---- pass A: row max + 11-bit float-order histogram ----
    float lmax = -INFINITY;
    for (int i = tid; i < VV; i += 1024) {
        float l = row[i];
        lmax = fmaxf(lmax, l);
        atomicAdd(&hist[enc_f32(l) >> 21], 1u);
    }
    red[tid] = lmax;
    __syncthreads();
    for (int s = 512; s > 0; s >>= 1) {
        if (tid < s) red[tid] = fmaxf(red[tid], red[tid + s]);
        __syncthreads();
    }
    if (tid == 0) {
        float m = red[0];
        m_sh = m;
        int t = (int)(enc_f32(m) >> 21);   // bins above max are empty
        unsigned int cum = 0u;
        for (; t >= 0; --t) { cum += hist[t]; if (cum >= 64u) break; }
        if (t < 0) t = 0;
        thresh_sh = ((unsigned int)t) << 21;
    }
    __syncthreads();
    const float m = m_sh;
    const unsigned int thresh = thresh_sh;

    // ---- pass B: softmax denominator Z ----
    float z = 0.0f;
    for (int i = tid; i < VV; i += 1024) z += expf(row[i] - m);
    red[tid] = z;
    __syncthreads();
    for (int s = 512; s > 0; s >>= 1) {
        if (tid < s) red[tid] += red[tid + s];
        __syncthreads();
    }
    const float Z = red[0];
    __syncthreads();

    // ---- pass C: collect candidates keyed by (prob desc, idx asc) ----
    for (int i = tid; i < VV; i += 1024) {
        float l = row[i];
        if (enc_f32(l) >= thresh) {
            float p = expf(l - m) / Z;     // exact ref softmax element
            unsigned int slot = atomicAdd(&cnt_sh, 1u);
            if (slot < NCAND)
                arr[slot] = ((unsigned long long)enc_f32(p) << 32)
                          | (unsigned long long)(~(unsigned int)i);
        }
    }
    __syncthreads();

    // ---- bitonic sort, descending (zeros sink to the end) ----
    for (int k = 2; k <= NCAND; k <<= 1) {
        for (int j = k >> 1; j > 0; j >>= 1) {
            for (int t = tid; t < NCAND; t += 1024) {
                int ixj = t ^ j;
                if (ixj > t) {
                    unsigned long long a = arr[t], c = arr[ixj];
                    bool desc = ((t & k) == 0);
                    if (desc ? (a < c) : (a > c)) { arr[t] = c; arr[ixj] = a; }
                }
            }
            __syncthreads();
        }
    }

    // ---- decode top-64 (p positive: enc = bits | 0x80000000) ----
    if (tid < 64) {
        unsigned long long key = arr[tid];
        p_arr[tid]   = __uint_as_float((unsigned int)(key >> 32) & 0x7FFFFFFFu);
        idx_arr[tid] = ~((unsigned int)(key & 0xFFFFFFFFull));
    }
    __syncthreads();

    // ---- sequential fp32 cumsum + top-p/top-k keep mask (np order) ----
    if (tid == 0) {
        float cum = 0.0f, S = 0.0f;
        unsigned long long keep = 0ull;
        const float tp = top_ps[b];
        const int   tk = top_ks[b];
        for (int r = 0; r < 64; ++r) {
            float p = p_arr[r];
            cum = cum + p;
            float excl = cum - p;          // ref: cum - probs_sort elementwise
            if (!(excl > tp) && (r < tk)) { keep |= (1ull << r); S = S + p; }
        }
        S_sh = S; keep_sh = keep;
    }
    __syncthreads();

    // ---- gumbel-max over kept set (exact jax.random.categorical(key(42))) ----
    if (tid < 64) {
        unsigned long long pk = 0ull;
        if ((keep_sh >> tid) & 1ull) {
            float q  = p_arr[tid] / S_sh;
            float lp = logf(q);
            unsigned int idx = idx_arr[tid];
            float g = gumbel_at((unsigned int)b * (unsigned int)VV + idx);
            float vf = lp + g;
            pk = ((unsigned long long)enc_f32(vf) << 32)
               | (unsigned long long)(~idx);
        }
        for (int off = 1; off < 64; off <<= 1) {
            unsigned long long o = __shfl_xor(pk, off, 64);
            if (o > pk) pk = o;
        }
        if (tid == 0) {
            unsigned int token = ~((unsigned int)(pk & 0xFFFFFFFFull));
            dout[b] = (float)token;
        }
    }
}

extern "C" void kernel_launch(void* const* d_in, const int* in_sizes, int n_in,
                              void* d_out, int out_size, void* d_ws, size_t ws_size,
                              hipStream_t stream) {
    const float* emb   = (const float*)d_in[0];
    const float* hid   = (const float*)d_in[1];
    const int*   pos   = (const int*)d_in[2];
    const float* temps = (const float*)d_in[3];
    const float* tps   = (const float*)d_in[4];
    const int*   tks   = (const int*)d_in[5];
    float* out = (float*)d_out;

    gemv_kernel<<<dim3(VV / 16), dim3(256), 0, stream>>>(emb, hid, pos, temps, out);
    sample_kernel<<<dim3(BB), dim3(1024), 0, stream>>>(out, tps, tks);
}

// Round 5
// 653.283 us; speedup vs baseline: 6.2268x; 6.2268x over previous
//
#include <hip/hip_runtime.h>
#include <stdint.h>
#include <math.h>

#define VV 128000
#define DD 2048
#define BB 32
#define SS 8
#define NCAND 4096

// jax_threefry_partitionable 32-bit stream: counter=(0,flat), bits = o0 ^ o1.  (verified R4)
#define TF_VARIANT 1

// ---------------- threefry2x32 core (key = (0, 42) from jax.random.key(42)) ----------------
__device__ __forceinline__ uint32_t rotl32(uint32_t x, uint32_t r) {
    return (x << r) | (x >> (32u - r));
}

__device__ __forceinline__ void threefry2x32(uint32_t c0, uint32_t c1,
                                             uint32_t& o0, uint32_t& o1) {
    const uint32_t k0 = 0u, k1 = 42u;
    const uint32_t k2 = 0x1BD11BDAu ^ k0 ^ k1;
    uint32_t x0 = c0 + k0;
    uint32_t x1 = c1 + k1;
    #define TF_ROUND(r) { x0 += x1; x1 = rotl32(x1, r); x1 ^= x0; }
    TF_ROUND(13) TF_ROUND(15) TF_ROUND(26) TF_ROUND(6)
    x0 += k1; x1 += k2 + 1u;
    TF_ROUND(17) TF_ROUND(29) TF_ROUND(16) TF_ROUND(24)
    x0 += k2; x1 += k0 + 2u;
    TF_ROUND(13) TF_ROUND(15) TF_ROUND(26) TF_ROUND(6)
    x0 += k0; x1 += k1 + 3u;
    TF_ROUND(17) TF_ROUND(29) TF_ROUND(16) TF_ROUND(24)
    x0 += k1; x1 += k2 + 4u;
    TF_ROUND(13) TF_ROUND(15) TF_ROUND(26) TF_ROUND(6)
    x0 += k2; x1 += k0 + 5u;
    #undef TF_ROUND
    o0 = x0; o1 = x1;
}

__device__ float gumbel_at(uint32_t flat) {
    uint32_t o0, o1;
    threefry2x32(0u, flat, o0, o1);   // counter (hi=0, lo=flat)
    uint32_t bits = o0 ^ o1;          // partitionable 32-bit path
    // exact jax.random.uniform(minval=tiny) -> gumbel
    uint32_t fb = (bits >> 9) | 0x3F800000u;
    float f = __uint_as_float(fb) - 1.0f;       // [0,1), multiples of 2^-23
    const float TINY = 1.17549435e-38f;
    float u = (f > 0.0f) ? f : TINY;
    return -logf(-logf(u));
}

__device__ __forceinline__ uint32_t enc_f32(float f) {
    uint32_t u = __float_as_uint(f);
    return u ^ (0x80000000u | (uint32_t)(((int32_t)u) >> 31));  // order-preserving
}

// ---------------- K1: logits = softcap(hs @ emb^T)/temp ----------------
// Block: 16 v-rows x 32 batches. 4 waves split batches (8 each).
// Lane: kl = lane&15 (k-split over 16 lanes), vl = lane>>4 (v-quad group).
// Thread register tile: 4 v x 8 b (acc = 32 VGPRs). No spill (waves_per_eu caps target at 4/EU).
__global__ __launch_bounds__(256) __attribute__((amdgpu_waves_per_eu(2, 4)))
void gemv_kernel(
    const float* __restrict__ emb, const float* __restrict__ hidden,
    const int* __restrict__ outpos, const float* __restrict__ temps,
    float* __restrict__ out)
{
    __shared__ float hs[BB][256];      // 32 KB k-chunk of hidden states
    __shared__ float lout[16][33];     // transpose buffer (padded stride 33)

    const int tid   = threadIdx.x;
    const int w     = tid >> 6;        // wave 0..3 -> batch group
    const int lane  = tid & 63;
    const int kl    = lane & 15;       // k-slice lane
    const int vl    = lane >> 4;       // 0..3: v-quad within block
    const int vbase = blockIdx.x * 16;
    const int pos   = outpos[0];
    const int bb0   = w * 8;

    float acc[4][8];
    #pragma unroll
    for (int v = 0; v < 4; ++v)
        #pragma unroll
        for (int b = 0; b < 8; ++b) acc[v][b] = 0.0f;

    for (int kc = 0; kc < DD; kc += 256) {
        __syncthreads();
        // cooperative stage: hs[32][256] <- hidden[b][pos][kc..kc+255]
        #pragma unroll
        for (int it = 0; it < 8; ++it) {
            int f4  = tid + it * 256;          // float4 index 0..2047
            int row = f4 >> 6;                 // 64 float4 per row
            int col = (f4 & 63) << 2;
            float4 v4 = *reinterpret_cast<const float4*>(
                hidden + (size_t)row * (SS * DD) + (size_t)pos * DD + kc + col);
            *reinterpret_cast<float4*>(&hs[row][col]) = v4;
        }
        __syncthreads();
        #pragma unroll
        for (int q = 0; q < 4; ++q) {
            const int ko = q * 64 + kl * 4;
            float4 e[4];
            #pragma unroll
            for (int v = 0; v < 4; ++v)
                e[v] = *reinterpret_cast<const float4*>(
                    emb + (size_t)(vbase + vl * 4 + v) * DD + kc + ko);
            #pragma unroll
            for (int b = 0; b < 8; ++b) {
                const float4 h = *reinterpret_cast<const float4*>(&hs[bb0 + b][ko]);
                #pragma unroll
                for (int v = 0; v < 4; ++v) {
                    acc[v][b] += e[v].x * h.x;
                    acc[v][b] += e[v].y * h.y;
                    acc[v][b] += e[v].z * h.z;
                    acc[v][b] += e[v].w * h.w;
                }
            }
        }
    }

    // reduce partial dots across the 16 k-lanes
    #pragma unroll
    for (int v = 0; v < 4; ++v)
        #pragma unroll
        for (int b = 0; b < 8; ++b) {
            float a = acc[v][b];
            a += __shfl_xor(a, 1, 64);
            a += __shfl_xor(a, 2, 64);
            a += __shfl_xor(a, 4, 64);
            a += __shfl_xor(a, 8, 64);
            acc[v][b] = a;
        }

    if (kl == 0) {
        #pragma unroll
        for (int v = 0; v < 4; ++v)
            #pragma unroll
            for (int b = 0; b < 8; ++b) {
                float raw = acc[v][b];
                float l = tanhf(raw / 30.0f) * 30.0f;   // final logit softcapping
                l = l / temps[bb0 + b];                  // temperature (division, as in R4)
                lout[vl * 4 + v][bb0 + b] = l;
            }
    }
    __syncthreads();
    // coalesced store: 512 logits per block
    #pragma unroll
    for (int r = 0; r < 2; ++r) {
        int idx = tid + r * 256;
        int b2  = idx >> 4;
        int vv2 = idx & 15;
        out[32 + (size_t)b2 * VV + vbase + vv2] = lout[vv2][b2];
    }
}

// ---------------- K2: per-row top-64 (prob-sorted, stable) + exact-RNG categorical ----------------
__global__ __launch_bounds__(1024) void sample_kernel(
    float* __restrict__ dout, const float* __restrict__ top_ps,
    const int* __restrict__ top_ks)
{
    const int b   = blockIdx.x;
    const int tid = threadIdx.x;
    const float* row = dout + 32 + (size_t)b * VV;

    __shared__ unsigned int hist[2048];            // 8KB
    __shared__ unsigned long long arr[NCAND];      // 32KB: (enc(p)<<32)|~idx
    __shared__ float red[1024];                    // 4KB
    __shared__ float m_sh;
    __shared__ unsigned int thresh_sh;
    __shared__ unsigned int cnt_sh;
    __shared__ float p_arr[64];
    __shared__ unsigned int idx_arr[64];
    __shared__ float S_sh;
    __shared__ unsigned long long keep_sh;

    for (int i = tid; i < 2048; i += 1024) hist[i] = 0u;
    for (int i = tid; i < NCAND; i += 1024) arr[i] = 0ull;
    if (tid == 0) cnt_sh = 0u;
    __syncthreads();

    // ---- pass A: row max + 11-bit float-order histogram ----
    float lmax = -INFINITY;
    for (int i = tid; i < VV; i += 1024) {
        float l = row[i];
        lmax = fmaxf(lmax, l);
        atomicAdd(&hist[enc_f32(l) >> 21], 1u);
    }
    red[tid] = lmax;
    __syncthreads();
    for (int s = 512; s > 0; s >>= 1) {
        if (tid < s) red[tid] = fmaxf(red[tid], red[tid + s]);
        __syncthreads();
    }
    if (tid == 0) {
        float m = red[0];
        m_sh = m;
        int t = (int)(enc_f32(m) >> 21);
        unsigned int cum = 0u;
        for (; t >= 0; --t) { cum += hist[t]; if (cum >= 64u) break; }
        if (t < 0) t = 0;
        thresh_sh = ((unsigned int)t) << 21;
    }
    __syncthreads();
    const float m = m_sh;
    const unsigned int thresh = thresh_sh;

    // ---- pass B: softmax denominator Z ----
    float z = 0.0f;
    for (int i = tid; i < VV; i += 1024) z += expf(row[i] - m);
    red[tid] = z;
    __syncthreads();
    for (int s = 512; s > 0; s >>= 1) {
        if (tid < s) red[tid] += red[tid + s];
        __syncthreads();
    }
    const float Z = red[0];
    __syncthreads();

    // ---- pass C: collect candidates keyed by (prob desc, idx asc) ----
    for (int i = tid; i < VV; i += 1024) {
        float l = row[i];
        if (enc_f32(l) >= thresh) {
            float p = expf(l - m) / Z;
            unsigned int slot = atomicAdd(&cnt_sh, 1u);
            if (slot < NCAND)
                arr[slot] = ((unsigned long long)enc_f32(p) << 32)
                          | (unsigned long long)(~(unsigned int)i);
        }
    }
    __syncthreads();

    // ---- bitonic sort, descending (zeros sink to the end) ----
    for (int k = 2; k <= NCAND; k <<= 1) {
        for (int j = k >> 1; j > 0; j >>= 1) {
            for (int t = tid; t < NCAND; t += 1024) {
                int ixj = t ^ j;
                if (ixj > t) {
                    unsigned long long a = arr[t], c = arr[ixj];
                    bool desc = ((t & k) == 0);
                    if (desc ? (a < c) : (a > c)) { arr[t] = c; arr[ixj] = a; }
                }
            }
            __syncthreads();
        }
    }

    // ---- decode top-64 ----
    if (tid < 64) {
        unsigned long long key = arr[tid];
        p_arr[tid]   = __uint_as_float((unsigned int)(key >> 32) & 0x7FFFFFFFu);
        idx_arr[tid] = ~((unsigned int)(key & 0xFFFFFFFFull));
    }
    __syncthreads();

    // ---- sequential fp32 cumsum + top-p/top-k keep mask (np order) ----
    if (tid == 0) {
        float cum = 0.0f, S = 0.0f;
        unsigned long long keep = 0ull;
        const float tp = top_ps[b];
        const int   tk = top_ks[b];
        for (int r = 0; r < 64; ++r) {
            float p = p_arr[r];
            cum = cum + p;
            float excl = cum - p;
            if (!(excl > tp) && (r < tk)) { keep |= (1ull << r); S = S + p; }
        }
        S_sh = S; keep_sh = keep;
    }
    __syncthreads();

    // ---- gumbel-max over kept set (exact jax.random.categorical(key(42))) ----
    if (tid < 64) {
        unsigned long long pk = 0ull;
        if ((keep_sh >> tid) & 1ull) {
            float q  = p_arr[tid] / S_sh;
            float lp = logf(q);
            unsigned int idx = idx_arr[tid];
            float g = gumbel_at((unsigned int)b * (unsigned int)VV + idx);
            float vf = lp + g;
            pk = ((unsigned long long)enc_f32(vf) << 32)
               | (unsigned long long)(~idx);
        }
        for (int off = 1; off < 64; off <<= 1) {
            unsigned long long o = __shfl_xor(pk, off, 64);
            if (o > pk) pk = o;
        }
        if (tid == 0) {
            unsigned int token = ~((unsigned int)(pk & 0xFFFFFFFFull));
            dout[b] = (float)token;
        }
    }
}

extern "C" void kernel_launch(void* const* d_in, const int* in_sizes, int n_in,
                              void* d_out, int out_size, void* d_ws, size_t ws_size,
                              hipStream_t stream) {
    const float* emb   = (const float*)d_in[0];
    const float* hid   = (const float*)d_in[1];
    const int*   pos   = (const int*)d_in[2];
    const float* temps = (const float*)d_in[3];
    const float* tps   = (const float*)d_in[4];
    const int*   tks   = (const int*)d_in[5];
    float* out = (float*)d_out;

    gemv_kernel<<<dim3(VV / 16), dim3(256), 0, stream>>>(emb, hid, pos, temps, out);
    sample_kernel<<<dim3(BB), dim3(1024), 0, stream>>>(out, tps, tks);
}